// Round 1
// baseline (75.537 us; speedup 1.0000x reference)
//
#include <hip/hip_runtime.h>

// Problem constants (from reference)
#define NT     101            // (SLEN - PTILE)/STEP + 1 = (208-8)/2+1
#define PTILES (NT * NT)      // 10201 tiles
#define BATCH  16
#define NSRC   100
#define NTILES (BATCH * PTILES)   // 163216

// Each source lands in at most one tile per dim:
//   on(b,p,s)  iff  y in (2r+2.5, 2r+4.5) and x in (2c+2.5, 2c+4.5)
// where (y,x) = locs[b,s,:] * 207, p = r*101 + c.
// argsort(-is_on) is stable -> slots are the first-two on-sources in s order;
// off slots are exactly zero in all outputs.

__global__ __launch_bounds__(256)
void ImageEncoder_41944650613092_kernel(const float* __restrict__ locs,
                                        const float* __restrict__ fluxes,
                                        float* __restrict__ out)
{
    int t = blockIdx.x * blockDim.x + threadIdx.x;
    if (t >= NTILES) return;

    int b   = t / PTILES;
    int p   = t - b * PTILES;
    int row = p / NT;
    int col = p - row * NT;

    float ly = (float)(row * 2) + 2.5f;   // left  edge, dim 0
    float lx = (float)(col * 2) + 2.5f;   // left  edge, dim 1
    float ry = ly + 2.0f;                 // right edge, dim 0
    float rx = lx + 2.0f;                 // right edge, dim 1

    const float* lb = locs + b * (NSRC * 2);

    int s0 = -1, s1 = -1, cnt = 0;
    #pragma unroll 4
    for (int s = 0; s < NSRC; ++s) {
        float y = lb[2 * s]     * 207.0f;
        float x = lb[2 * s + 1] * 207.0f;
        bool on = (y > ly) & (y < ry) & (x > lx) & (x < rx);
        if (on) {
            if (cnt == 0)      s0 = s;
            else if (cnt == 1) s1 = s;
            ++cnt;
        }
    }

    // Output layout: concatenated flat, float32
    //   [0,              NTILES)     n_sources
    //   [NTILES,         NTILES*5)   tile_locs   (NTILES, 2, 2)
    //   [NTILES*5,       NTILES*15)  tile_fluxes (NTILES, 2, 5)
    //   [NTILES*15,      NTILES*17)  tile_is_on  (NTILES, 2)
    float* out_n = out;
    float* out_l = out + NTILES;
    float* out_f = out + (size_t)NTILES * 5;
    float* out_o = out + (size_t)NTILES * 15;

    out_n[t] = fminf((float)cnt, 2.0f);

    float l4[4]   = {0.f, 0.f, 0.f, 0.f};
    float f10[10] = {0.f, 0.f, 0.f, 0.f, 0.f, 0.f, 0.f, 0.f, 0.f, 0.f};
    float o2[2]   = {0.f, 0.f};

    int sel0 = s0, sel1 = s1;
    #pragma unroll
    for (int k = 0; k < 2; ++k) {
        int s = (k == 0) ? sel0 : sel1;
        if (s >= 0) {
            float y = lb[2 * s]     * 207.0f;
            float x = lb[2 * s + 1] * 207.0f;
            l4[2 * k]     = (y - ly) * 0.5f;   // /scale, scale = PTILE-2*EDGE = 2
            l4[2 * k + 1] = (x - lx) * 0.5f;
            const float* fb = fluxes + (size_t)(b * NSRC + s) * 5;
            #pragma unroll
            for (int j = 0; j < 5; ++j) f10[5 * k + j] = fb[j];
            o2[k] = 1.0f;
        }
    }

    *(float4*)(out_l + (size_t)t * 4) = make_float4(l4[0], l4[1], l4[2], l4[3]);
    #pragma unroll
    for (int j = 0; j < 5; ++j)
        *(float2*)(out_f + (size_t)t * 10 + 2 * j) = make_float2(f10[2 * j], f10[2 * j + 1]);
    *(float2*)(out_o + (size_t)t * 2) = make_float2(o2[0], o2[1]);
}

extern "C" void kernel_launch(void* const* d_in, const int* in_sizes, int n_in,
                              void* d_out, int out_size, void* d_ws, size_t ws_size,
                              hipStream_t stream) {
    const float* locs   = (const float*)d_in[0];   // (16, 100, 2) f32
    const float* fluxes = (const float*)d_in[1];   // (16, 100, 5) f32
    float* out = (float*)d_out;                    // 17 * NTILES = 2774672 f32

    int threads = 256;
    int blocks  = (NTILES + threads - 1) / threads;   // 638
    ImageEncoder_41944650613092_kernel<<<blocks, threads, 0, stream>>>(locs, fluxes, out);
}

// Round 2
// 61.891 us; speedup vs baseline: 1.2205x; 1.2205x over previous
//
#include <hip/hip_runtime.h>

// Problem constants (from reference)
#define NT     101            // (SLEN - PTILE)/STEP + 1 = (208-8)/2+1
#define PTILES (NT * NT)      // 10201 tiles
#define BATCH  16
#define NSRC   100
#define NTILES (BATCH * PTILES)   // 163216
#define PBLK   256            // tiles per block
#define NBLKX  ((PTILES + PBLK - 1) / PBLK)   // 40

// Each source is "on" in at most one tile per dim:
//   on(b,p,s) iff y in (2r+2.5, 2r+4.5) and x in (2c+2.5, 2c+4.5),
//   (y,x) = locs[b,s,:]*207, p = r*101+c.
// argsort(-is_on) is stable -> the MAXDET=2 slots are the first two
// on-sources in s order; off slots are exactly zero in every output.
//
// Strategy: block = (batch, 256-tile strip). Stage the batch's 100 sources
// into LDS ONCE, pre-folded to a candidate tile id (validated with the exact
// reference f32 comparisons). Inner scan: 1 LDS int compare per source.

__global__ __launch_bounds__(256)
void ImageEncoder_41944650613092_kernel(const float* __restrict__ locs,
                                        const float* __restrict__ fluxes,
                                        float* __restrict__ out)
{
    __shared__ __align__(16) int   s_t[NSRC];   // candidate tile id or -1
    __shared__ float s_y[NSRC];
    __shared__ float s_x[NSRC];

    const int tid = threadIdx.x;
    const int b   = blockIdx.y;
    const int p   = blockIdx.x * PBLK + tid;

    // ---- stage batch sources into LDS (threads 0..99) ----
    if (tid < NSRC) {
        const float2 yx = ((const float2*)(locs + b * (NSRC * 2)))[tid];
        const float yp = yx.x * 207.0f;
        const float xp = yx.y * 207.0f;
        int r = (int)floorf((yp - 2.5f) * 0.5f);
        int c = (int)floorf((xp - 2.5f) * 0.5f);
        bool ok = (r >= 0) & (r < NT) & (c >= 0) & (c < NT);
        if (ok) {
            // exact reference comparisons (bit-identical decision)
            const float ly = (float)(2 * r) + 2.5f;
            const float lx = (float)(2 * c) + 2.5f;
            ok = (yp > ly) & (yp < ly + 2.0f) & (xp > lx) & (xp < lx + 2.0f);
        }
        s_t[tid] = ok ? (r * NT + c) : -1;
        s_y[tid] = yp;
        s_x[tid] = xp;
    }
    __syncthreads();

    if (p >= PTILES) return;
    const int t = b * PTILES + p;

    // ---- scan: first two sources whose candidate tile == p ----
    int cnt = 0, s0 = -1, s1 = -1;
    #pragma unroll
    for (int s4 = 0; s4 < NSRC; s4 += 4) {
        const int4 tq = *(const int4*)&s_t[s4];
        #pragma unroll
        for (int j = 0; j < 4; ++j) {
            const int tc = (j == 0) ? tq.x : (j == 1) ? tq.y : (j == 2) ? tq.z : tq.w;
            const bool m = (tc == p);
            if (m) {
                if (cnt == 0)      s0 = s4 + j;
                else if (cnt == 1) s1 = s4 + j;
                ++cnt;
            }
        }
    }

    // Output layout (flat f32, reference return order):
    //   [0,          NTILES)    n_sources
    //   [NTILES,     NTILES*5)  tile_locs   (NTILES,2,2)
    //   [NTILES*5,   NTILES*15) tile_fluxes (NTILES,2,5)
    //   [NTILES*15,  NTILES*17) tile_is_on  (NTILES,2)
    float* out_n = out;
    float* out_l = out + NTILES;
    float* out_f = out + (size_t)NTILES * 5;
    float* out_o = out + (size_t)NTILES * 15;

    out_n[t] = fminf((float)cnt, 2.0f);

    float l4[4]   = {0.f, 0.f, 0.f, 0.f};
    float f10[10] = {0.f, 0.f, 0.f, 0.f, 0.f, 0.f, 0.f, 0.f, 0.f, 0.f};
    float o2[2]   = {0.f, 0.f};

    const int row = p / NT;
    const int col = p - row * NT;
    const float ly = (float)(2 * row) + 2.5f;
    const float lx = (float)(2 * col) + 2.5f;

    #pragma unroll
    for (int k = 0; k < 2; ++k) {
        const int s = (k == 0) ? s0 : s1;
        if (s >= 0) {
            l4[2 * k]     = (s_y[s] - ly) * 0.5f;   // /scale, scale = 2
            l4[2 * k + 1] = (s_x[s] - lx) * 0.5f;
            const float* fb = fluxes + (size_t)(b * NSRC + s) * 5;
            #pragma unroll
            for (int j = 0; j < 5; ++j) f10[5 * k + j] = fb[j];
            o2[k] = 1.0f;
        }
    }

    *(float4*)(out_l + (size_t)t * 4) = make_float4(l4[0], l4[1], l4[2], l4[3]);
    #pragma unroll
    for (int j = 0; j < 5; ++j)
        *(float2*)(out_f + (size_t)t * 10 + 2 * j) = make_float2(f10[2 * j], f10[2 * j + 1]);
    *(float2*)(out_o + (size_t)t * 2) = make_float2(o2[0], o2[1]);
}

extern "C" void kernel_launch(void* const* d_in, const int* in_sizes, int n_in,
                              void* d_out, int out_size, void* d_ws, size_t ws_size,
                              hipStream_t stream) {
    const float* locs   = (const float*)d_in[0];   // (16, 100, 2) f32
    const float* fluxes = (const float*)d_in[1];   // (16, 100, 5) f32
    float* out = (float*)d_out;                    // 17 * NTILES f32

    dim3 grid(NBLKX, BATCH);   // 40 x 16 = 640 blocks
    ImageEncoder_41944650613092_kernel<<<grid, 256, 0, stream>>>(locs, fluxes, out);
}

// Round 3
// 60.000 us; speedup vs baseline: 1.2589x; 1.0315x over previous
//
#include <hip/hip_runtime.h>

// Problem constants (from reference)
#define NT     101            // (SLEN - PTILE)/STEP + 1 = (208-8)/2+1
#define PTILES (NT * NT)      // 10201 tiles
#define BATCH  16
#define NSRC   100
#define NTILES (BATCH * PTILES)   // 163216
#define PBLK   256            // tiles per block
#define NBLKX  ((PTILES + PBLK - 1) / PBLK)   // 40

// Each source is "on" in at most one tile:
//   on(b,p,s) iff y in (2r+2.5, 2r+4.5) and x in (2c+2.5, 2c+4.5),
//   (y,x) = locs[b,s,:]*207, p = r*101+c.
// argsort(-is_on) is stable -> the MAXDET=2 slots are the first two
// on-sources in s order; off slots are exactly zero in every output.
//
// Block = (batch, 256-tile strip). Stage 100 sources, pre-fold to candidate
// tile, then ballot-compact (s-order preserved) ONLY the ~2.5 sources whose
// tile lies in this strip. Per-tile scan is then ~3 iterations, not 100.
// Flux outputs (stride 10 floats/tile) staged in LDS and written coalesced.

__global__ __launch_bounds__(256)
void ImageEncoder_41944650613092_kernel(const float* __restrict__ locs,
                                        const float* __restrict__ fluxes,
                                        float* __restrict__ out)
{
    __shared__ int   s_cnt[2];
    __shared__ int   s_tc[NSRC];     // compacted candidate tile ids (s-order)
    __shared__ int   s_id[NSRC];     // compacted source indices
    __shared__ float s_y[NSRC];
    __shared__ float s_x[NSRC];
    __shared__ float s_f[PBLK * 10]; // flux output staging (10 KB)

    const int tid   = threadIdx.x;
    const int b     = blockIdx.y;
    const int pbase = blockIdx.x * PBLK;
    const int p     = pbase + tid;

    // ---- stage + filter ----
    bool  m  = false;
    int   tc = -1;
    float yp = 0.f, xp = 0.f;
    if (tid < NSRC) {
        const float2 yx = ((const float2*)(locs + b * (NSRC * 2)))[tid];
        yp = yx.x * 207.0f;
        xp = yx.y * 207.0f;
        int r = (int)floorf((yp - 2.5f) * 0.5f);
        int c = (int)floorf((xp - 2.5f) * 0.5f);
        bool ok = (r >= 0) & (r < NT) & (c >= 0) & (c < NT);
        if (ok) {
            // exact reference comparisons (bit-identical decision)
            const float ly = (float)(2 * r) + 2.5f;
            const float lx = (float)(2 * c) + 2.5f;
            ok = (yp > ly) & (yp < ly + 2.0f) & (xp > lx) & (xp < lx + 2.0f);
        }
        tc = r * NT + c;
        m  = ok & (tc >= pbase) & (tc < pbase + PBLK);
    }

    // ---- order-preserving compaction (waves 0 and 1 only hold sources) ----
    int pos = 0;
    if (tid < 128) {
        const unsigned long long ball = __ballot(m);
        const int lane = tid & 63;
        const int wave = tid >> 6;
        if (lane == 0) s_cnt[wave] = __popcll(ball);
        pos = __popcll(ball & ((1ull << lane) - 1ull));
    }
    __syncthreads();
    if (m) {
        const int idx = ((tid >> 6) ? s_cnt[0] : 0) + pos;
        s_tc[idx] = tc;
        s_id[idx] = tid;
        s_y[idx]  = yp;
        s_x[idx]  = xp;
    }
    const int total = s_cnt[0] + s_cnt[1];
    __syncthreads();

    // ---- scan the few candidates; first two matches in s order ----
    int cnt = 0, i0 = -1, i1 = -1;
    for (int i = 0; i < total; ++i) {   // block-uniform bound, ~2-3 typical
        if (s_tc[i] == p) {
            if (cnt == 0)      i0 = i;
            else if (cnt == 1) i1 = i;
            ++cnt;
        }
    }

    // ---- build per-tile outputs ----
    float l4[4]   = {0.f, 0.f, 0.f, 0.f};
    float f10[10] = {0.f, 0.f, 0.f, 0.f, 0.f, 0.f, 0.f, 0.f, 0.f, 0.f};
    float o2[2]   = {0.f, 0.f};

    const int row = p / NT;
    const int col = p - row * NT;
    const float ly = (float)(2 * row) + 2.5f;
    const float lx = (float)(2 * col) + 2.5f;

    #pragma unroll
    for (int k = 0; k < 2; ++k) {
        const int i = (k == 0) ? i0 : i1;
        if (i >= 0) {
            l4[2 * k]     = (s_y[i] - ly) * 0.5f;   // /scale, scale = 2
            l4[2 * k + 1] = (s_x[i] - lx) * 0.5f;
            const float* fb = fluxes + (size_t)(b * NSRC + s_id[i]) * 5;
            #pragma unroll
            for (int j = 0; j < 5; ++j) f10[5 * k + j] = fb[j];
            o2[k] = 1.0f;
        }
    }

    // Output layout (flat f32, reference return order):
    //   [0,          NTILES)    n_sources
    //   [NTILES,     NTILES*5)  tile_locs   (NTILES,2,2)
    //   [NTILES*5,   NTILES*15) tile_fluxes (NTILES,2,5)
    //   [NTILES*15,  NTILES*17) tile_is_on  (NTILES,2)
    float* out_n = out;
    float* out_l = out + NTILES;
    float* out_f = out + (size_t)NTILES * 5;
    float* out_o = out + (size_t)NTILES * 15;

    const int t = b * PTILES + p;
    if (p < PTILES) {
        out_n[t] = fminf((float)cnt, 2.0f);
        *(float4*)(out_l + (size_t)t * 4) = make_float4(l4[0], l4[1], l4[2], l4[3]);
        *(float2*)(out_o + (size_t)t * 2) = make_float2(o2[0], o2[1]);
    }

    // ---- flux section: stage in LDS, store coalesced ----
    #pragma unroll
    for (int j = 0; j < 10; ++j) s_f[tid * 10 + j] = f10[j];
    __syncthreads();

    const int nvalid = min(PTILES - pbase, PBLK);      // 256, or 217 last strip
    const int nfl2   = nvalid * 5;                     // float2 count (nvalid*10/2)
    float2* dst = (float2*)(out_f + ((size_t)b * PTILES + pbase) * 10);
    const float2* src = (const float2*)s_f;
    for (int i = tid; i < nfl2; i += PBLK) dst[i] = src[i];
}

extern "C" void kernel_launch(void* const* d_in, const int* in_sizes, int n_in,
                              void* d_out, int out_size, void* d_ws, size_t ws_size,
                              hipStream_t stream) {
    const float* locs   = (const float*)d_in[0];   // (16, 100, 2) f32
    const float* fluxes = (const float*)d_in[1];   // (16, 100, 5) f32
    float* out = (float*)d_out;                    // 17 * NTILES f32

    dim3 grid(NBLKX, BATCH);   // 40 x 16 = 640 blocks
    ImageEncoder_41944650613092_kernel<<<grid, 256, 0, stream>>>(locs, fluxes, out);
}